// Round 14
// baseline (141.890 us; speedup 1.0000x reference)
//
#include <hip/hip_runtime.h>
#include <hip/hip_bf16.h>
#include <stdint.h>

typedef __attribute__((ext_vector_type(4))) float f32x4;
typedef __attribute__((ext_vector_type(2))) float f32x2;
typedef __attribute__((ext_vector_type(8))) __bf16 bf16x8;

__device__ __forceinline__ unsigned short f2bf(float f) {
  unsigned u = __float_as_uint(f);
  unsigned r = (u + 0x7fffu + ((u >> 16) & 1u)) >> 16;
  return (unsigned short)r;
}
__device__ __forceinline__ float bf2f(unsigned short h) {
  return __uint_as_float(((unsigned)h) << 16);
}

__device__ __forceinline__ void load_lds16(const void* g, void* l) {
  __builtin_amdgcn_global_load_lds(
      (const __attribute__((address_space(1))) unsigned int*)g,
      (__attribute__((address_space(3))) unsigned int*)l, 16, 0, 0);
}

// Counted vmcnt wait (never 0 in steady state) + scheduling fence (rule #18).
__device__ __forceinline__ void vwait(int n) {
  switch (n) {
    case 8: asm volatile("s_waitcnt vmcnt(8)" ::: "memory"); break;
    case 6: asm volatile("s_waitcnt vmcnt(6)" ::: "memory"); break;
    case 4: asm volatile("s_waitcnt vmcnt(4)" ::: "memory"); break;
    case 3: asm volatile("s_waitcnt vmcnt(3)" ::: "memory"); break;
    case 2: asm volatile("s_waitcnt vmcnt(2)" ::: "memory"); break;
    default: asm volatile("s_waitcnt vmcnt(0)" ::: "memory"); break;
  }
  __builtin_amdgcn_sched_barrier(0);
}

// ---------------------------------------------------------------------------
// Kernel 1 (merged): blocks 0..2047 = three_nn scan (8 lanes/point,
// branchless top-3, d' = |a|^2 - 2 p.a); blocks 2048..6143 = prep work
// (W transposes -> bf16, points2 -> bf16, stats zero). The VALU-bound scan
// time-shares CUs with the memory-bound convert.
__global__ __launch_bounds__(256) void nn_prep_kernel(
    const float* __restrict__ xyz1, const float* __restrict__ xyz2,
    const float* __restrict__ W0, const float* __restrict__ W1,
    const float* __restrict__ P2f, float* __restrict__ W3,
    int* __restrict__ I3, unsigned short* __restrict__ W0t,
    unsigned short* __restrict__ W1t, unsigned short* __restrict__ P2,
    float* __restrict__ stats) {
  const int bid = blockIdx.x;
  const int tid = threadIdx.x;
  if (bid >= 2048) {
    const int pid = bid - 2048;
    const int id = pid * 256 + tid;
    if (pid == 0) {
      for (int i = tid; i < 1536; i += 256) stats[i] = 0.f;
    }
    if (id < 256 * 384) {
      int n = id / 384, k = id - n * 384;
      W0t[id] = f2bf(W0[k * 256 + n]);
    }
    if (id < 128 * 256) {
      int n = id / 256, k = id - n * 256;
      W1t[id] = f2bf(W1[k * 128 + n]);
    }
    if (id < 1048576) {
      f32x4 v = ((const f32x4*)P2f)[id];
      ushort4 o = make_ushort4(f2bf(v[0]), f2bf(v[1]), f2bf(v[2]), f2bf(v[3]));
      ((ushort4*)P2)[id] = o;
    }
    return;
  }

  __shared__ __align__(16) float sx[1024];
  __shared__ __align__(16) float sy[1024];
  __shared__ __align__(16) float sz[1024];
  __shared__ __align__(16) float sn[1024];
  const int b = bid >> 7;
  const int n0 = (bid & 127) * 32;

  const float* xb = xyz2 + (size_t)b * 3072;
  for (int i = tid; i < 1024; i += 256) {
    float x = xb[i * 3 + 0], y = xb[i * 3 + 1], z = xb[i * 3 + 2];
    sx[i] = x; sy[i] = y; sz[i] = z;
    sn[i] = x * x + y * y + z * z;
  }
  __syncthreads();

  const int pt = tid >> 3, q = tid & 7;
  const int n = n0 + pt;
  const float* p = xyz1 + ((size_t)b * 4096 + n) * 3;
  const float px = p[0], py = p[1], pz = p[2];
  const float cx = -2.f * px, cy = -2.f * py, cz = -2.f * pz;

  float d0 = 3e38f, d1 = 3e38f, d2 = 3e38f;
  int i0 = 0, i1 = 0, i2 = 0;
  auto ins = [&](float e, int j) {
    const bool c0 = e < d0, c1 = e < d1, c2 = e < d2;
    const float nd2 = c1 ? d1 : (c2 ? e : d2);
    const int   ni2 = c1 ? i1 : (c2 ? j : i2);
    const float nd1 = c0 ? d0 : (c1 ? e : d1);
    const int   ni1 = c0 ? i0 : (c1 ? j : i1);
    d0 = c0 ? e : d0; i0 = c0 ? j : i0;
    d1 = nd1; i1 = ni1;
    d2 = nd2; i2 = ni2;
  };

  const f32x4* vx = (const f32x4*)sx;
  const f32x4* vy = (const f32x4*)sy;
  const f32x4* vz = (const f32x4*)sz;
  const f32x4* vn = (const f32x4*)sn;
  for (int jj = 0; jj < 32; jj++) {
    const int c = jj * 8 + q;
    f32x4 ax = vx[c], ay = vy[c], az = vz[c], an = vn[c];
#pragma unroll
    for (int u = 0; u < 4; u++) {
      float d = fmaf(ax[u], cx, fmaf(ay[u], cy, fmaf(az[u], cz, an[u])));
      ins(d, c * 4 + u);
    }
  }
#pragma unroll
  for (int off = 1; off <= 4; off <<= 1) {
    float e0 = __shfl_xor(d0, off, 64);
    float e1 = __shfl_xor(d1, off, 64);
    float e2 = __shfl_xor(d2, off, 64);
    int j0 = __shfl_xor(i0, off, 64);
    int j1 = __shfl_xor(i1, off, 64);
    int j2 = __shfl_xor(i2, off, 64);
    ins(e0, j0); ins(e1, j1); ins(e2, j2);
  }

  if (q == 0) {
    const float pn = fmaf(px, px, fmaf(py, py, pz * pz));
    float t0 = fmaxf(d0 + pn, 1e-10f);
    float t1 = fmaxf(d1 + pn, 1e-10f);
    float t2 = fmaxf(d2 + pn, 1e-10f);
    float w0 = 1.f / t0, w1 = 1.f / t1, w2 = 1.f / t2;
    float inv = 1.f / (w0 + w1 + w2);
    const int row = b * 4096 + n;
    W3[row * 3 + 0] = w0 * inv;
    W3[row * 3 + 1] = w1 * inv;
    W3[row * 3 + 2] = w2 * inv;
    I3[row * 3 + 0] = (b << 10) + i0;
    I3[row * 3 + 1] = (b << 10) + i1;
    I3[row * 3 + 2] = (b << 10) + i2;
  }
}

// ---------------------------------------------------------------------------
// Kernel 2: gather + weighted interp + concat -> X bf16 [65536][384]
__global__ __launch_bounds__(256) void interp_concat_kernel(
    const float* __restrict__ points1, const unsigned short* __restrict__ P2,
    const float* __restrict__ W3, const int* __restrict__ I3,
    unsigned short* __restrict__ X) {
  const int gw = blockIdx.x * 4 + (threadIdx.x >> 6);
  const int lane = threadIdx.x & 63;
#pragma unroll 2
  for (int pp = 0; pp < 8; pp++) {
    const int row = gw * 8 + pp;
    const float w0 = W3[row * 3 + 0], w1 = W3[row * 3 + 1], w2 = W3[row * 3 + 2];
    const int g0 = I3[row * 3 + 0], g1 = I3[row * 3 + 1], g2 = I3[row * 3 + 2];
    const ushort4 a0 = *(const ushort4*)(P2 + (size_t)g0 * 256 + lane * 4);
    const ushort4 a1 = *(const ushort4*)(P2 + (size_t)g1 * 256 + lane * 4);
    const ushort4 a2 = *(const ushort4*)(P2 + (size_t)g2 * 256 + lane * 4);
    float o0 = bf2f(a0.x) * w0 + bf2f(a1.x) * w1 + bf2f(a2.x) * w2;
    float o1 = bf2f(a0.y) * w0 + bf2f(a1.y) * w1 + bf2f(a2.y) * w2;
    float o2 = bf2f(a0.z) * w0 + bf2f(a1.z) * w1 + bf2f(a2.z) * w2;
    float o3 = bf2f(a0.w) * w0 + bf2f(a1.w) * w1 + bf2f(a2.w) * w2;
    unsigned int lo = (unsigned)f2bf(o0) | ((unsigned)f2bf(o1) << 16);
    unsigned int hi = (unsigned)f2bf(o2) | ((unsigned)f2bf(o3) << 16);
    *(uint2*)(X + (size_t)row * 384 + lane * 4) = make_uint2(lo, hi);
    const f32x2 qv = ((const f32x2*)(points1 + (size_t)row * 128))[lane];
    unsigned int pq = (unsigned)f2bf(qv.x) | ((unsigned)f2bf(qv.y) << 16);
    *(unsigned int*)(X + (size_t)row * 384 + 256 + lane * 2) = pq;
  }
}

// ---------------------------------------------------------------------------
// GEMM1: [65536][384] x [384][256] + b0 -> Y bf16 (pre-BN) + col stats.
// Tile 256x256, 1024 thr / 16 waves (4m x 4n, wave = 64x64), BK=32.
// 4-buffer LDS (128 KB), depth-3 prefetch, counted vmcnt(4), raw s_barrier.
// Per-thread staging: 1 A chunk + 1 B chunk (16B each).
__global__ __launch_bounds__(1024) void gemm1_kernel(
    const unsigned short* __restrict__ A, const unsigned short* __restrict__ Bt,
    const float* __restrict__ bvec, unsigned short* __restrict__ Y,
    float* __restrict__ ssum, float* __restrict__ ssq) {
  __shared__ __align__(16) char smem[131072];  // 4 bufs x (A 16KB + B 16KB)
  unsigned short* S = (unsigned short*)smem;
  const int m0 = blockIdx.x * 256;
  const int tid = threadIdx.x;
  const int wv = tid >> 6, lane = tid & 63;
  const int wm = wv >> 2, wn = wv & 3;
  f32x4 acc[4][4] = {};

  // Stage tile t into buf t&3. Chunk id c = tid: A row c>>2, k-part c&3,
  // source k-chunk XOR-swizzled by row&3 (both-sides swizzle, rule #21).
  auto stage = [&](int t) {
    const int k0 = t * 32;
    unsigned short* Ab = S + (t & 3) * 16384;
    unsigned short* Bb = Ab + 8192;
    const int row = tid >> 2, kp = tid & 3;
    const int gk = (kp ^ (row & 3)) * 8;
    load_lds16(A + (size_t)(m0 + row) * 384 + k0 + gk, Ab + wv * 512);
    load_lds16(Bt + (size_t)row * 384 + k0 + gk, Bb + wv * 512);
  };

  stage(0); stage(1); stage(2);  // 6 loads/thread in flight
  for (int t = 0; t < 12; ++t) {
    const int w = 11 - t;
    vwait(w >= 2 ? 4 : w * 2);
    __builtin_amdgcn_s_barrier();
    __builtin_amdgcn_sched_barrier(0);
    if (t < 9) stage(t + 3);
    const unsigned short* Ab = S + (t & 3) * 16384;
    const unsigned short* Bb = Ab + 8192;
    const int q = lane >> 4;
    bf16x8 af[4], bfr[4];
#pragma unroll
    for (int mf = 0; mf < 4; mf++) {
      const int r = wm * 64 + mf * 16 + (lane & 15);
      af[mf] = *(const bf16x8*)(Ab + r * 32 + (q ^ (r & 3)) * 8);
    }
#pragma unroll
    for (int nf = 0; nf < 4; nf++) {
      const int c = wn * 64 + nf * 16 + (lane & 15);
      bfr[nf] = *(const bf16x8*)(Bb + c * 32 + (q ^ (c & 3)) * 8);
    }
    __builtin_amdgcn_s_setprio(1);
#pragma unroll
    for (int mf = 0; mf < 4; mf++)
#pragma unroll
      for (int nf = 0; nf < 4; nf++)
        acc[mf][nf] = __builtin_amdgcn_mfma_f32_16x16x32_bf16(
            af[mf], bfr[nf], acc[mf][nf], 0, 0, 0);
    __builtin_amdgcn_s_setprio(0);
  }
  __syncthreads();  // pipeline empty; reuse smem for epilogue

  // Epilogue: per-wave 64x64 bf16 patch (8KB), then 128B row segments.
  float s[4] = {0, 0, 0, 0}, s2[4] = {0, 0, 0, 0};
  unsigned short* ep = S + wv * 4096;  // 8 KB per wave, 16 waves = 128 KB
#pragma unroll
  for (int mf = 0; mf < 4; mf++) {
#pragma unroll
    for (int nf = 0; nf < 4; nf++) {
      const float bv = bvec[wn * 64 + nf * 16 + (lane & 15)];
      f32x4 v = acc[mf][nf];
#pragma unroll
      for (int r = 0; r < 4; r++) {
        float y = v[r] + bv;
        s[nf] += y;
        s2[nf] += y * y;
        ep[(mf * 16 + (lane >> 4) * 4 + r) * 64 + nf * 16 + (lane & 15)] =
            f2bf(y);
      }
    }
  }
#pragma unroll
  for (int it = 0; it < 8; it++) {
    const int rr = it * 8 + (lane >> 3);
    *(uint4*)(Y + (size_t)(m0 + wm * 64 + rr) * 256 + wn * 64 + (lane & 7) * 8) =
        *(const uint4*)(ep + rr * 64 + (lane & 7) * 8);
  }

#pragma unroll
  for (int nf = 0; nf < 4; nf++) {
    s[nf] += __shfl_xor(s[nf], 16, 64);
    s[nf] += __shfl_xor(s[nf], 32, 64);
    s2[nf] += __shfl_xor(s2[nf], 16, 64);
    s2[nf] += __shfl_xor(s2[nf], 32, 64);
  }
  if (lane < 16) {
#pragma unroll
    for (int nf = 0; nf < 4; nf++) {
      const int col = wn * 64 + nf * 16 + lane;
      atomicAdd(&ssum[col], s[nf]);
      atomicAdd(&ssq[col], s2[nf]);
    }
  }
}

// ---------------------------------------------------------------------------
// GEMM2: BN1 coefficients computed in prolog from global sums (bn_fin folded);
// A = relu(BN1(Y)) applied during reg-staging; x W1t + b1 -> Y2 bf16 + stats.
// Tile 256x128, 512 thr / 8 waves, BK=32, 8 K-tiles; depth-3, counted vmcnt(6).
__device__ __forceinline__ uint4 bnpack8(bf16x8 r, f32x4 s0, f32x4 s1,
                                         f32x4 c0, f32x4 c1) {
  unsigned short o[8];
#pragma unroll
  for (int j = 0; j < 8; j++) {
    const float sj = j < 4 ? s0[j] : s1[j - 4];
    const float cj = j < 4 ? c0[j] : c1[j - 4];
    o[j] = f2bf(fmaxf(0.f, fmaf((float)r[j], sj, cj)));
  }
  return make_uint4((unsigned)o[0] | ((unsigned)o[1] << 16),
                    (unsigned)o[2] | ((unsigned)o[3] << 16),
                    (unsigned)o[4] | ((unsigned)o[5] << 16),
                    (unsigned)o[6] | ((unsigned)o[7] << 16));
}

__global__ __launch_bounds__(512) void gemm2_kernel(
    const unsigned short* __restrict__ Yin, const unsigned short* __restrict__ Bt,
    const float* __restrict__ sum1, const float* __restrict__ sq1,
    const float* __restrict__ g0, const float* __restrict__ be0,
    const float* __restrict__ bvec, unsigned short* __restrict__ Y2,
    float* __restrict__ ssum, float* __restrict__ ssq) {
  __shared__ __align__(16) char smem[100352];  // 4*24576 + 2048
  unsigned short* S = (unsigned short*)smem;
  float* scL = (float*)(smem + 98304);
  float* biL = scL + 256;
  const int m0 = blockIdx.x * 256;
  const int tid = threadIdx.x;
  const int wv = tid >> 6, lane = tid & 63;
  const int wm = wv >> 2, wn = wv & 3;
  f32x4 acc[8][2] = {};

  if (tid < 256) {  // bn_fin folded: BN1 scale/bias from global sums
    const float invN = 1.0f / 65536.0f;
    float mu = sum1[tid] * invN;
    float var = sq1[tid] * invN - mu * mu;
    float sc = g0[tid] * rsqrtf(var + 1e-3f);
    scL[tid] = sc;
    biL[tid] = be0[tid] - mu * sc;
  }
  __syncthreads();

  bf16x8 arg[3][2];
  // Per tile: 2 A reg-loads + 1 B global_load_lds = 3 vmem ops.
  auto stageT = [&](int t, bf16x8(&ar)[2]) {
    const int k0 = t * 32;
#pragma unroll
    for (int j = 0; j < 2; j++) {
      const int c = tid + j * 512;  // A chunk 0..1023
      const int row = c >> 2, kp = c & 3;
      const int gk = (kp ^ (row & 3)) * 8;
      ar[j] = *(const bf16x8*)(Yin + (size_t)(m0 + row) * 256 + k0 + gk);
    }
    const int cb = wv * 64 + lane;  // B chunk 0..511
    const int rowb = cb >> 2, kpb = cb & 3;
    const int gkb = (kpb ^ (rowb & 3)) * 8;
    load_lds16(Bt + (size_t)rowb * 256 + k0 + gkb,
               S + (t & 3) * 12288 + 8192 + wv * 512);
  };

  stageT(0, arg[0]); stageT(1, arg[1]); stageT(2, arg[2]);
#pragma unroll
  for (int t = 0; t < 8; ++t) {
    const int w = 7 - t;
    vwait(w >= 2 ? 6 : w * 3);  // tile t's A regs + B in LDS ready
    // BN+ReLU on A(t) regs, ds_write into Abuf[t&3] (own chunks only).
    unsigned short* Ab = S + (t & 3) * 12288;
#pragma unroll
    for (int j = 0; j < 2; j++) {
      const int c = tid + j * 512;
      const int row = c >> 2, kp = c & 3;
      const int gk = (kp ^ (row & 3)) * 8;
      const int kch = t * 32 + gk;
      const f32x4 sA = *(const f32x4*)(scL + kch);
      const f32x4 sB = *(const f32x4*)(scL + kch + 4);
      const f32x4 cA = *(const f32x4*)(biL + kch);
      const f32x4 cB = *(const f32x4*)(biL + kch + 4);
      *(uint4*)(Ab + c * 8) = bnpack8(arg[t % 3][j], sA, sB, cA, cB);
    }
    asm volatile("s_waitcnt lgkmcnt(0)" ::: "memory");
    __builtin_amdgcn_sched_barrier(0);
    __builtin_amdgcn_s_barrier();
    __builtin_amdgcn_sched_barrier(0);
    if (t < 5) stageT(t + 3, arg[t % 3]);  // slot just consumed
    const unsigned short* Bb = S + (t & 3) * 12288 + 8192;
    const int q = lane >> 4;
    bf16x8 af[8], bfr[2];
#pragma unroll
    for (int mf = 0; mf < 8; mf++) {
      const int r = wm * 128 + mf * 16 + (lane & 15);
      af[mf] = *(const bf16x8*)(Ab + r * 32 + (q ^ (r & 3)) * 8);
    }
#pragma unroll
    for (int nf = 0; nf < 2; nf++) {
      const int c = wn * 32 + nf * 16 + (lane & 15);
      bfr[nf] = *(const bf16x8*)(Bb + c * 32 + (q ^ (c & 3)) * 8);
    }
    __builtin_amdgcn_s_setprio(1);
#pragma unroll
    for (int mf = 0; mf < 8; mf++)
#pragma unroll
      for (int nf = 0; nf < 2; nf++)
        acc[mf][nf] = __builtin_amdgcn_mfma_f32_16x16x32_bf16(
            af[mf], bfr[nf], acc[mf][nf], 0, 0, 0);
    __builtin_amdgcn_s_setprio(0);
  }
  __syncthreads();  // reuse smem for epilogue

  float s[2] = {0, 0}, s2[2] = {0, 0};
  unsigned short* ep = S + wv * 4096;  // 8KB per wave: 128 rows x 32 cols
#pragma unroll
  for (int mf = 0; mf < 8; mf++) {
#pragma unroll
    for (int nf = 0; nf < 2; nf++) {
      const float bv = bvec[wn * 32 + nf * 16 + (lane & 15)];
      f32x4 v = acc[mf][nf];
#pragma unroll
      for (int r = 0; r < 4; r++) {
        float y = v[r] + bv;
        s[nf] += y;
        s2[nf] += y * y;
        ep[(mf * 16 + (lane >> 4) * 4 + r) * 32 + nf * 16 + (lane & 15)] =
            f2bf(y);
      }
    }
  }
#pragma unroll
  for (int it = 0; it < 8; it++) {
    const int rr = it * 16 + (lane >> 2);
    *(uint4*)(Y2 + (size_t)(m0 + wm * 128 + rr) * 128 + wn * 32 + (lane & 3) * 8) =
        *(const uint4*)(ep + rr * 32 + (lane & 3) * 8);
  }

#pragma unroll
  for (int nf = 0; nf < 2; nf++) {
    s[nf] += __shfl_xor(s[nf], 16, 64);
    s[nf] += __shfl_xor(s[nf], 32, 64);
    s2[nf] += __shfl_xor(s2[nf], 16, 64);
    s2[nf] += __shfl_xor(s2[nf], 32, 64);
  }
  if (lane < 16) {
#pragma unroll
    for (int nf = 0; nf < 2; nf++) {
      const int col = wn * 32 + nf * 16 + lane;
      atomicAdd(&ssum[col], s[nf]);
      atomicAdd(&ssq[col], s2[nf]);
    }
  }
}

// ---------------------------------------------------------------------------
// BN2+ReLU (bn_fin folded into prolog): read Y2 bf16, write f32 d_out.
__global__ __launch_bounds__(256) void bnrelu_out_kernel(
    const unsigned short* __restrict__ Y2, const float* __restrict__ ssum,
    const float* __restrict__ ssq, const float* __restrict__ g,
    const float* __restrict__ be, float* __restrict__ out) {
  __shared__ __align__(16) float scL[128];
  __shared__ __align__(16) float biL[128];
  const int tid = threadIdx.x;
  if (tid < 128) {
    const float invN = 1.0f / 65536.0f;
    float mu = ssum[tid] * invN;
    float var = ssq[tid] * invN - mu * mu;
    float sc = g[tid] * rsqrtf(var + 1e-3f);
    scL[tid] = sc;
    biL[tid] = be[tid] - mu * sc;
  }
  __syncthreads();

  const size_t i = ((size_t)blockIdx.x * 256 + tid) * 8;
  const int c0 = (int)(i & 127);
  uint4 v = *(const uint4*)(Y2 + i);
  const f32x4 sA = *(const f32x4*)(scL + c0);
  const f32x4 sB = *(const f32x4*)(scL + c0 + 4);
  const f32x4 bA = *(const f32x4*)(biL + c0);
  const f32x4 bB = *(const f32x4*)(biL + c0 + 4);
  unsigned int w[4] = {v.x, v.y, v.z, v.w};
  f32x4 o0, o1;
#pragma unroll
  for (int q = 0; q < 2; q++) {
    o0[q * 2 + 0] = fmaxf(0.f, fmaf(bf2f((unsigned short)(w[q] & 0xffff)), sA[q * 2 + 0], bA[q * 2 + 0]));
    o0[q * 2 + 1] = fmaxf(0.f, fmaf(bf2f((unsigned short)(w[q] >> 16)),   sA[q * 2 + 1], bA[q * 2 + 1]));
    o1[q * 2 + 0] = fmaxf(0.f, fmaf(bf2f((unsigned short)(w[q + 2] & 0xffff)), sB[q * 2 + 0], bB[q * 2 + 0]));
    o1[q * 2 + 1] = fmaxf(0.f, fmaf(bf2f((unsigned short)(w[q + 2] >> 16)),   sB[q * 2 + 1], bB[q * 2 + 1]));
  }
  *(f32x4*)(out + i) = o0;
  *(f32x4*)(out + i + 4) = o1;
}

// ---------------------------------------------------------------------------
extern "C" void kernel_launch(void* const* d_in, const int* in_sizes, int n_in,
                              void* d_out, int out_size, void* d_ws,
                              size_t ws_size, hipStream_t stream) {
  const float* xyz1 = (const float*)d_in[0];
  const float* points1 = (const float*)d_in[1];
  const float* xyz2 = (const float*)d_in[2];
  const float* points2 = (const float*)d_in[3];
  const float* W0 = (const float*)d_in[4];
  const float* b0 = (const float*)d_in[5];
  const float* g0 = (const float*)d_in[6];
  const float* be0 = (const float*)d_in[7];
  const float* W1 = (const float*)d_in[8];
  const float* b1 = (const float*)d_in[9];
  const float* g1 = (const float*)d_in[10];
  const float* be1 = (const float*)d_in[11];

  char* ws = (char*)d_ws;
  unsigned short* X = (unsigned short*)(ws);              // [65536][384] bf16
  unsigned short* Y2 = (unsigned short*)(ws);             // [65536][128] bf16 (aliases X; X dead after GEMM1)
  unsigned short* Y = (unsigned short*)(ws + 50331648);   // [65536][256] bf16
  unsigned short* P2 = (unsigned short*)(ws + 50331648);  // 8 MB bf16 points2 (dies before GEMM1)
  float* W3 = (float*)(ws + 50331648 + 8388608);
  int* I3 = (int*)(ws + 50331648 + 8388608 + 786432);
  unsigned short* W0t = (unsigned short*)(ws + 83886080);
  unsigned short* W1t = (unsigned short*)(ws + 84082688);
  float* stats = (float*)(ws + 84148224);
  float* sum1 = stats, *sq1 = stats + 256;
  float* sum2 = stats + 1024, *sq2 = stats + 1152;
  float* outF = (float*)d_out;

  nn_prep_kernel<<<6144, 256, 0, stream>>>(xyz1, xyz2, W0, W1, points2, W3, I3,
                                           W0t, W1t, P2, stats);
  interp_concat_kernel<<<2048, 256, 0, stream>>>(points1, P2, W3, I3, X);
  gemm1_kernel<<<256, 1024, 0, stream>>>(X, W0t, b0, Y, sum1, sq1);
  gemm2_kernel<<<256, 512, 0, stream>>>(Y, W1t, sum1, sq1, g0, be0, b1, Y2,
                                        sum2, sq2);
  bnrelu_out_kernel<<<4096, 256, 0, stream>>>(Y2, sum2, sq2, g1, be1, outF);
}

// Round 15
// 127.658 us; speedup vs baseline: 1.1115x; 1.1115x over previous
//
#include <hip/hip_runtime.h>
#include <hip/hip_bf16.h>
#include <stdint.h>

typedef __attribute__((ext_vector_type(4))) float f32x4;
typedef __attribute__((ext_vector_type(2))) float f32x2;
typedef __attribute__((ext_vector_type(8))) __bf16 bf16x8;

__device__ __forceinline__ unsigned short f2bf(float f) {
  unsigned u = __float_as_uint(f);
  unsigned r = (u + 0x7fffu + ((u >> 16) & 1u)) >> 16;
  return (unsigned short)r;
}
__device__ __forceinline__ float bf2f(unsigned short h) {
  return __uint_as_float(((unsigned)h) << 16);
}

__device__ __forceinline__ void load_lds16(const void* g, void* l) {
  __builtin_amdgcn_global_load_lds(
      (const __attribute__((address_space(1))) unsigned int*)g,
      (__attribute__((address_space(3))) unsigned int*)l, 16, 0, 0);
}

// Counted vmcnt wait (never 0 in steady state) + scheduling fence (rule #18).
__device__ __forceinline__ void vwait(int n) {
  switch (n) {
    case 8: asm volatile("s_waitcnt vmcnt(8)" ::: "memory"); break;
    case 6: asm volatile("s_waitcnt vmcnt(6)" ::: "memory"); break;
    case 4: asm volatile("s_waitcnt vmcnt(4)" ::: "memory"); break;
    case 3: asm volatile("s_waitcnt vmcnt(3)" ::: "memory"); break;
    default: asm volatile("s_waitcnt vmcnt(0)" ::: "memory"); break;
  }
  __builtin_amdgcn_sched_barrier(0);
}

// ---------------------------------------------------------------------------
// Kernel 1 (merged): blocks 0..2047 = three_nn scan (8 lanes/point,
// branchless top-3, d' = |a|^2 - 2 p.a); blocks 2048..6143 = prep work
// (W transposes -> bf16, points2 -> bf16, stats zero).
__global__ __launch_bounds__(256) void nn_prep_kernel(
    const float* __restrict__ xyz1, const float* __restrict__ xyz2,
    const float* __restrict__ W0, const float* __restrict__ W1,
    const float* __restrict__ P2f, float* __restrict__ W3,
    int* __restrict__ I3, unsigned short* __restrict__ W0t,
    unsigned short* __restrict__ W1t, unsigned short* __restrict__ P2,
    float* __restrict__ stats) {
  const int bid = blockIdx.x;
  const int tid = threadIdx.x;
  if (bid >= 2048) {
    const int pid = bid - 2048;
    const int id = pid * 256 + tid;
    if (pid == 0) {
      for (int i = tid; i < 1536; i += 256) stats[i] = 0.f;
    }
    if (id < 256 * 384) {
      int n = id / 384, k = id - n * 384;
      W0t[id] = f2bf(W0[k * 256 + n]);
    }
    if (id < 128 * 256) {
      int n = id / 256, k = id - n * 256;
      W1t[id] = f2bf(W1[k * 128 + n]);
    }
    if (id < 1048576) {
      f32x4 v = ((const f32x4*)P2f)[id];
      ushort4 o = make_ushort4(f2bf(v[0]), f2bf(v[1]), f2bf(v[2]), f2bf(v[3]));
      ((ushort4*)P2)[id] = o;
    }
    return;
  }

  __shared__ __align__(16) float sx[1024];
  __shared__ __align__(16) float sy[1024];
  __shared__ __align__(16) float sz[1024];
  __shared__ __align__(16) float sn[1024];
  const int b = bid >> 7;
  const int n0 = (bid & 127) * 32;

  const float* xb = xyz2 + (size_t)b * 3072;
  for (int i = tid; i < 1024; i += 256) {
    float x = xb[i * 3 + 0], y = xb[i * 3 + 1], z = xb[i * 3 + 2];
    sx[i] = x; sy[i] = y; sz[i] = z;
    sn[i] = x * x + y * y + z * z;
  }
  __syncthreads();

  const int pt = tid >> 3, q = tid & 7;
  const int n = n0 + pt;
  const float* p = xyz1 + ((size_t)b * 4096 + n) * 3;
  const float px = p[0], py = p[1], pz = p[2];
  const float cx = -2.f * px, cy = -2.f * py, cz = -2.f * pz;

  float d0 = 3e38f, d1 = 3e38f, d2 = 3e38f;
  int i0 = 0, i1 = 0, i2 = 0;
  auto ins = [&](float e, int j) {
    const bool c0 = e < d0, c1 = e < d1, c2 = e < d2;
    const float nd2 = c1 ? d1 : (c2 ? e : d2);
    const int   ni2 = c1 ? i1 : (c2 ? j : i2);
    const float nd1 = c0 ? d0 : (c1 ? e : d1);
    const int   ni1 = c0 ? i0 : (c1 ? j : i1);
    d0 = c0 ? e : d0; i0 = c0 ? j : i0;
    d1 = nd1; i1 = ni1;
    d2 = nd2; i2 = ni2;
  };

  const f32x4* vx = (const f32x4*)sx;
  const f32x4* vy = (const f32x4*)sy;
  const f32x4* vz = (const f32x4*)sz;
  const f32x4* vn = (const f32x4*)sn;
  for (int jj = 0; jj < 32; jj++) {
    const int c = jj * 8 + q;
    f32x4 ax = vx[c], ay = vy[c], az = vz[c], an = vn[c];
#pragma unroll
    for (int u = 0; u < 4; u++) {
      float d = fmaf(ax[u], cx, fmaf(ay[u], cy, fmaf(az[u], cz, an[u])));
      ins(d, c * 4 + u);
    }
  }
#pragma unroll
  for (int off = 1; off <= 4; off <<= 1) {
    float e0 = __shfl_xor(d0, off, 64);
    float e1 = __shfl_xor(d1, off, 64);
    float e2 = __shfl_xor(d2, off, 64);
    int j0 = __shfl_xor(i0, off, 64);
    int j1 = __shfl_xor(i1, off, 64);
    int j2 = __shfl_xor(i2, off, 64);
    ins(e0, j0); ins(e1, j1); ins(e2, j2);
  }

  if (q == 0) {
    const float pn = fmaf(px, px, fmaf(py, py, pz * pz));
    float t0 = fmaxf(d0 + pn, 1e-10f);
    float t1 = fmaxf(d1 + pn, 1e-10f);
    float t2 = fmaxf(d2 + pn, 1e-10f);
    float w0 = 1.f / t0, w1 = 1.f / t1, w2 = 1.f / t2;
    float inv = 1.f / (w0 + w1 + w2);
    const int row = b * 4096 + n;
    W3[row * 3 + 0] = w0 * inv;
    W3[row * 3 + 1] = w1 * inv;
    W3[row * 3 + 2] = w2 * inv;
    I3[row * 3 + 0] = (b << 10) + i0;
    I3[row * 3 + 1] = (b << 10) + i1;
    I3[row * 3 + 2] = (b << 10) + i2;
  }
}

// ---------------------------------------------------------------------------
// Kernel 2: gather + weighted interp + concat -> X bf16 [65536][384]
__global__ __launch_bounds__(256) void interp_concat_kernel(
    const float* __restrict__ points1, const unsigned short* __restrict__ P2,
    const float* __restrict__ W3, const int* __restrict__ I3,
    unsigned short* __restrict__ X) {
  const int gw = blockIdx.x * 4 + (threadIdx.x >> 6);
  const int lane = threadIdx.x & 63;
#pragma unroll 2
  for (int pp = 0; pp < 8; pp++) {
    const int row = gw * 8 + pp;
    const float w0 = W3[row * 3 + 0], w1 = W3[row * 3 + 1], w2 = W3[row * 3 + 2];
    const int g0 = I3[row * 3 + 0], g1 = I3[row * 3 + 1], g2 = I3[row * 3 + 2];
    const ushort4 a0 = *(const ushort4*)(P2 + (size_t)g0 * 256 + lane * 4);
    const ushort4 a1 = *(const ushort4*)(P2 + (size_t)g1 * 256 + lane * 4);
    const ushort4 a2 = *(const ushort4*)(P2 + (size_t)g2 * 256 + lane * 4);
    float o0 = bf2f(a0.x) * w0 + bf2f(a1.x) * w1 + bf2f(a2.x) * w2;
    float o1 = bf2f(a0.y) * w0 + bf2f(a1.y) * w1 + bf2f(a2.y) * w2;
    float o2 = bf2f(a0.z) * w0 + bf2f(a1.z) * w1 + bf2f(a2.z) * w2;
    float o3 = bf2f(a0.w) * w0 + bf2f(a1.w) * w1 + bf2f(a2.w) * w2;
    unsigned int lo = (unsigned)f2bf(o0) | ((unsigned)f2bf(o1) << 16);
    unsigned int hi = (unsigned)f2bf(o2) | ((unsigned)f2bf(o3) << 16);
    *(uint2*)(X + (size_t)row * 384 + lane * 4) = make_uint2(lo, hi);
    const f32x2 qv = ((const f32x2*)(points1 + (size_t)row * 128))[lane];
    unsigned int pq = (unsigned)f2bf(qv.x) | ((unsigned)f2bf(qv.y) << 16);
    *(unsigned int*)(X + (size_t)row * 384 + 256 + lane * 2) = pq;
  }
}

// ---------------------------------------------------------------------------
// GEMM1 (R13-proven): [65536][384] x [384][256] + b0 -> Y bf16 + col stats.
// Tile 256x256, 512 thr / 8 waves (2m x 4n, wave = 128x64), BK=32.
// 4-buffer LDS (128 KB), depth-3 prefetch, counted vmcnt(8), raw s_barrier.
__global__ __launch_bounds__(512) void gemm1_kernel(
    const unsigned short* __restrict__ A, const unsigned short* __restrict__ Bt,
    const float* __restrict__ bvec, unsigned short* __restrict__ Y,
    float* __restrict__ ssum, float* __restrict__ ssq) {
  __shared__ __align__(16) char smem[131072];  // 4 bufs x (A 16KB + B 16KB)
  unsigned short* S = (unsigned short*)smem;
  const int m0 = blockIdx.x * 256;
  const int tid = threadIdx.x;
  const int wv = tid >> 6, lane = tid & 63;
  const int wm = wv >> 2, wn = wv & 3;
  f32x4 acc[8][4] = {};

  auto stage = [&](int t) {
    const int k0 = t * 32;
    unsigned short* Ab = S + (t & 3) * 16384;
    unsigned short* Bb = Ab + 8192;
#pragma unroll
    for (int i = 0; i < 2; i++) {
      const int c = (wv * 2 + i) * 64 + lane;  // chunk 0..1023
      const int row = c >> 2, kp = c & 3;
      const int gk = (kp ^ (row & 3)) * 8;
      load_lds16(A + (size_t)(m0 + row) * 384 + k0 + gk, Ab + (wv * 2 + i) * 512);
      load_lds16(Bt + (size_t)row * 384 + k0 + gk, Bb + (wv * 2 + i) * 512);
    }
  };

  stage(0); stage(1); stage(2);  // 12 loads in flight
  for (int t = 0; t < 12; ++t) {
    const int w = 11 - t;
    vwait(w >= 2 ? 8 : w * 4);
    __builtin_amdgcn_s_barrier();
    __builtin_amdgcn_sched_barrier(0);
    if (t < 9) stage(t + 3);
    const unsigned short* Ab = S + (t & 3) * 16384;
    const unsigned short* Bb = Ab + 8192;
    const int q = lane >> 4;
    bf16x8 af[8], bfr[4];
#pragma unroll
    for (int mf = 0; mf < 8; mf++) {
      const int r = wm * 128 + mf * 16 + (lane & 15);
      af[mf] = *(const bf16x8*)(Ab + r * 32 + (q ^ (r & 3)) * 8);
    }
#pragma unroll
    for (int nf = 0; nf < 4; nf++) {
      const int c = wn * 64 + nf * 16 + (lane & 15);
      bfr[nf] = *(const bf16x8*)(Bb + c * 32 + (q ^ (c & 3)) * 8);
    }
    __builtin_amdgcn_s_setprio(1);
#pragma unroll
    for (int mf = 0; mf < 8; mf++)
#pragma unroll
      for (int nf = 0; nf < 4; nf++)
        acc[mf][nf] = __builtin_amdgcn_mfma_f32_16x16x32_bf16(
            af[mf], bfr[nf], acc[mf][nf], 0, 0, 0);
    __builtin_amdgcn_s_setprio(0);
  }
  __syncthreads();  // pipeline empty; reuse smem for epilogue

  // Epilogue: per-wave 128x64 bf16 patch (16KB), then 128B row segments.
  float s[4] = {0, 0, 0, 0}, s2[4] = {0, 0, 0, 0};
  unsigned short* ep = S + wv * 8192;
#pragma unroll
  for (int mf = 0; mf < 8; mf++) {
#pragma unroll
    for (int nf = 0; nf < 4; nf++) {
      const float bv = bvec[wn * 64 + nf * 16 + (lane & 15)];
      f32x4 v = acc[mf][nf];
#pragma unroll
      for (int r = 0; r < 4; r++) {
        float y = v[r] + bv;
        s[nf] += y;
        s2[nf] += y * y;
        ep[(mf * 16 + (lane >> 4) * 4 + r) * 64 + nf * 16 + (lane & 15)] =
            f2bf(y);
      }
    }
  }
#pragma unroll
  for (int it = 0; it < 16; it++) {
    const int rr = it * 8 + (lane >> 3);
    *(uint4*)(Y + (size_t)(m0 + wm * 128 + rr) * 256 + wn * 64 + (lane & 7) * 8) =
        *(const uint4*)(ep + rr * 64 + (lane & 7) * 8);
  }

#pragma unroll
  for (int nf = 0; nf < 4; nf++) {
    s[nf] += __shfl_xor(s[nf], 16, 64);
    s[nf] += __shfl_xor(s[nf], 32, 64);
    s2[nf] += __shfl_xor(s2[nf], 16, 64);
    s2[nf] += __shfl_xor(s2[nf], 32, 64);
  }
  if (lane < 16) {
#pragma unroll
    for (int nf = 0; nf < 4; nf++) {
      const int col = wn * 64 + nf * 16 + lane;
      atomicAdd(&ssum[col], s[nf]);
      atomicAdd(&ssq[col], s2[nf]);
    }
  }
}

// ---------------------------------------------------------------------------
// GEMM2: BN1 coefficients computed in prolog from global sums (bn_fin folded);
// A = relu(BN1(Y)) applied during reg-staging; x W1t + b1 -> Y2 bf16 + stats.
// Tile 256x128, 512 thr / 8 waves, BK=32, 8 K-tiles; depth-3, counted vmcnt(6).
__device__ __forceinline__ uint4 bnpack8(bf16x8 r, f32x4 s0, f32x4 s1,
                                         f32x4 c0, f32x4 c1) {
  unsigned short o[8];
#pragma unroll
  for (int j = 0; j < 8; j++) {
    const float sj = j < 4 ? s0[j] : s1[j - 4];
    const float cj = j < 4 ? c0[j] : c1[j - 4];
    o[j] = f2bf(fmaxf(0.f, fmaf((float)r[j], sj, cj)));
  }
  return make_uint4((unsigned)o[0] | ((unsigned)o[1] << 16),
                    (unsigned)o[2] | ((unsigned)o[3] << 16),
                    (unsigned)o[4] | ((unsigned)o[5] << 16),
                    (unsigned)o[6] | ((unsigned)o[7] << 16));
}

__global__ __launch_bounds__(512) void gemm2_kernel(
    const unsigned short* __restrict__ Yin, const unsigned short* __restrict__ Bt,
    const float* __restrict__ sum1, const float* __restrict__ sq1,
    const float* __restrict__ g0, const float* __restrict__ be0,
    const float* __restrict__ bvec, unsigned short* __restrict__ Y2,
    float* __restrict__ ssum, float* __restrict__ ssq) {
  __shared__ __align__(16) char smem[100352];  // 4*24576 + 2048
  unsigned short* S = (unsigned short*)smem;
  float* scL = (float*)(smem + 98304);
  float* biL = scL + 256;
  const int m0 = blockIdx.x * 256;
  const int tid = threadIdx.x;
  const int wv = tid >> 6, lane = tid & 63;
  const int wm = wv >> 2, wn = wv & 3;
  f32x4 acc[8][2] = {};

  if (tid < 256) {  // bn_fin folded: BN1 scale/bias from global sums
    const float invN = 1.0f / 65536.0f;
    float mu = sum1[tid] * invN;
    float var = sq1[tid] * invN - mu * mu;
    float sc = g0[tid] * rsqrtf(var + 1e-3f);
    scL[tid] = sc;
    biL[tid] = be0[tid] - mu * sc;
  }
  __syncthreads();

  bf16x8 arg[3][2];
  // Per tile: 2 A reg-loads + 1 B global_load_lds = 3 vmem ops.
  auto stageT = [&](int t, bf16x8(&ar)[2]) {
    const int k0 = t * 32;
#pragma unroll
    for (int j = 0; j < 2; j++) {
      const int c = tid + j * 512;  // A chunk 0..1023
      const int row = c >> 2, kp = c & 3;
      const int gk = (kp ^ (row & 3)) * 8;
      ar[j] = *(const bf16x8*)(Yin + (size_t)(m0 + row) * 256 + k0 + gk);
    }
    const int cb = wv * 64 + lane;  // B chunk 0..511
    const int rowb = cb >> 2, kpb = cb & 3;
    const int gkb = (kpb ^ (rowb & 3)) * 8;
    load_lds16(Bt + (size_t)rowb * 256 + k0 + gkb,
               S + (t & 3) * 12288 + 8192 + wv * 512);
  };

  stageT(0, arg[0]); stageT(1, arg[1]); stageT(2, arg[2]);
#pragma unroll
  for (int t = 0; t < 8; ++t) {
    const int w = 7 - t;
    vwait(w >= 2 ? 6 : w * 3);  // tile t's A regs + B in LDS ready
    // BN+ReLU on A(t) regs, ds_write into Abuf[t&3] (own chunks only).
    unsigned short* Ab = S + (t & 3) * 12288;
#pragma unroll
    for (int j = 0; j < 2; j++) {
      const int c = tid + j * 512;
      const int row = c >> 2, kp = c & 3;
      const int gk = (kp ^ (row & 3)) * 8;
      const int kch = t * 32 + gk;
      const f32x4 sA = *(const f32x4*)(scL + kch);
      const f32x4 sB = *(const f32x4*)(scL + kch + 4);
      const f32x4 cA = *(const f32x4*)(biL + kch);
      const f32x4 cB = *(const f32x4*)(biL + kch + 4);
      *(uint4*)(Ab + c * 8) = bnpack8(arg[t % 3][j], sA, sB, cA, cB);
    }
    asm volatile("s_waitcnt lgkmcnt(0)" ::: "memory");
    __builtin_amdgcn_sched_barrier(0);
    __builtin_amdgcn_s_barrier();
    __builtin_amdgcn_sched_barrier(0);
    if (t < 5) stageT(t + 3, arg[t % 3]);  // slot just consumed
    const unsigned short* Bb = S + (t & 3) * 12288 + 8192;
    const int q = lane >> 4;
    bf16x8 af[8], bfr[2];
#pragma unroll
    for (int mf = 0; mf < 8; mf++) {
      const int r = wm * 128 + mf * 16 + (lane & 15);
      af[mf] = *(const bf16x8*)(Ab + r * 32 + (q ^ (r & 3)) * 8);
    }
#pragma unroll
    for (int nf = 0; nf < 2; nf++) {
      const int c = wn * 32 + nf * 16 + (lane & 15);
      bfr[nf] = *(const bf16x8*)(Bb + c * 32 + (q ^ (c & 3)) * 8);
    }
    __builtin_amdgcn_s_setprio(1);
#pragma unroll
    for (int mf = 0; mf < 8; mf++)
#pragma unroll
      for (int nf = 0; nf < 2; nf++)
        acc[mf][nf] = __builtin_amdgcn_mfma_f32_16x16x32_bf16(
            af[mf], bfr[nf], acc[mf][nf], 0, 0, 0);
    __builtin_amdgcn_s_setprio(0);
  }
  __syncthreads();  // reuse smem for epilogue

  float s[2] = {0, 0}, s2[2] = {0, 0};
  unsigned short* ep = S + wv * 4096;  // 8KB per wave: 128 rows x 32 cols
#pragma unroll
  for (int mf = 0; mf < 8; mf++) {
#pragma unroll
    for (int nf = 0; nf < 2; nf++) {
      const float bv = bvec[wn * 32 + nf * 16 + (lane & 15)];
      f32x4 v = acc[mf][nf];
#pragma unroll
      for (int r = 0; r < 4; r++) {
        float y = v[r] + bv;
        s[nf] += y;
        s2[nf] += y * y;
        ep[(mf * 16 + (lane >> 4) * 4 + r) * 32 + nf * 16 + (lane & 15)] =
            f2bf(y);
      }
    }
  }
#pragma unroll
  for (int it = 0; it < 8; it++) {
    const int rr = it * 16 + (lane >> 2);
    *(uint4*)(Y2 + (size_t)(m0 + wm * 128 + rr) * 128 + wn * 32 + (lane & 3) * 8) =
        *(const uint4*)(ep + rr * 32 + (lane & 3) * 8);
  }

#pragma unroll
  for (int nf = 0; nf < 2; nf++) {
    s[nf] += __shfl_xor(s[nf], 16, 64);
    s[nf] += __shfl_xor(s[nf], 32, 64);
    s2[nf] += __shfl_xor(s2[nf], 16, 64);
    s2[nf] += __shfl_xor(s2[nf], 32, 64);
  }
  if (lane < 16) {
#pragma unroll
    for (int nf = 0; nf < 2; nf++) {
      const int col = wn * 32 + nf * 16 + lane;
      atomicAdd(&ssum[col], s[nf]);
      atomicAdd(&ssq[col], s2[nf]);
    }
  }
}

// ---------------------------------------------------------------------------
// BN2+ReLU (bn_fin folded into prolog): read Y2 bf16, write f32 d_out.
__global__ __launch_bounds__(256) void bnrelu_out_kernel(
    const unsigned short* __restrict__ Y2, const float* __restrict__ ssum,
    const float* __restrict__ ssq, const float* __restrict__ g,
    const float* __restrict__ be, float* __restrict__ out) {
  __shared__ __align__(16) float scL[128];
  __shared__ __align__(16) float biL[128];
  const int tid = threadIdx.x;
  if (tid < 128) {
    const float invN = 1.0f / 65536.0f;
    float mu = ssum[tid] * invN;
    float var = ssq[tid] * invN - mu * mu;
    float sc = g[tid] * rsqrtf(var + 1e-3f);
    scL[tid] = sc;
    biL[tid] = be[tid] - mu * sc;
  }
  __syncthreads();

  const size_t i = ((size_t)blockIdx.x * 256 + tid) * 8;
  const int c0 = (int)(i & 127);
  uint4 v = *(const uint4*)(Y2 + i);
  const f32x4 sA = *(const f32x4*)(scL + c0);
  const f32x4 sB = *(const f32x4*)(scL + c0 + 4);
  const f32x4 bA = *(const f32x4*)(biL + c0);
  const f32x4 bB = *(const f32x4*)(biL + c0 + 4);
  unsigned int w[4] = {v.x, v.y, v.z, v.w};
  f32x4 o0, o1;
#pragma unroll
  for (int q = 0; q < 2; q++) {
    o0[q * 2 + 0] = fmaxf(0.f, fmaf(bf2f((unsigned short)(w[q] & 0xffff)), sA[q * 2 + 0], bA[q * 2 + 0]));
    o0[q * 2 + 1] = fmaxf(0.f, fmaf(bf2f((unsigned short)(w[q] >> 16)),   sA[q * 2 + 1], bA[q * 2 + 1]));
    o1[q * 2 + 0] = fmaxf(0.f, fmaf(bf2f((unsigned short)(w[q + 2] & 0xffff)), sB[q * 2 + 0], bB[q * 2 + 0]));
    o1[q * 2 + 1] = fmaxf(0.f, fmaf(bf2f((unsigned short)(w[q + 2] >> 16)),   sB[q * 2 + 1], bB[q * 2 + 1]));
  }
  *(f32x4*)(out + i) = o0;
  *(f32x4*)(out + i + 4) = o1;
}

// ---------------------------------------------------------------------------
extern "C" void kernel_launch(void* const* d_in, const int* in_sizes, int n_in,
                              void* d_out, int out_size, void* d_ws,
                              size_t ws_size, hipStream_t stream) {
  const float* xyz1 = (const float*)d_in[0];
  const float* points1 = (const float*)d_in[1];
  const float* xyz2 = (const float*)d_in[2];
  const float* points2 = (const float*)d_in[3];
  const float* W0 = (const float*)d_in[4];
  const float* b0 = (const float*)d_in[5];
  const float* g0 = (const float*)d_in[6];
  const float* be0 = (const float*)d_in[7];
  const float* W1 = (const float*)d_in[8];
  const float* b1 = (const float*)d_in[9];
  const float* g1 = (const float*)d_in[10];
  const float* be1 = (const float*)d_in[11];

  char* ws = (char*)d_ws;
  unsigned short* X = (unsigned short*)(ws);              // [65536][384] bf16
  unsigned short* Y2 = (unsigned short*)(ws);             // [65536][128] bf16 (aliases X; X dead after GEMM1)
  unsigned short* Y = (unsigned short*)(ws + 50331648);   // [65536][256] bf16
  unsigned short* P2 = (unsigned short*)(ws + 50331648);  // 8 MB bf16 points2 (dies before GEMM1)
  float* W3 = (float*)(ws + 50331648 + 8388608);
  int* I3 = (int*)(ws + 50331648 + 8388608 + 786432);
  unsigned short* W0t = (unsigned short*)(ws + 83886080);
  unsigned short* W1t = (unsigned short*)(ws + 84082688);
  float* stats = (float*)(ws + 84148224);
  float* sum1 = stats, *sq1 = stats + 256;
  float* sum2 = stats + 1024, *sq2 = stats + 1152;
  float* outF = (float*)d_out;

  nn_prep_kernel<<<6144, 256, 0, stream>>>(xyz1, xyz2, W0, W1, points2, W3, I3,
                                           W0t, W1t, P2, stats);
  interp_concat_kernel<<<2048, 256, 0, stream>>>(points1, P2, W3, I3, X);
  gemm1_kernel<<<256, 512, 0, stream>>>(X, W0t, b0, Y, sum1, sq1);
  gemm2_kernel<<<256, 512, 0, stream>>>(Y, W1t, sum1, sq1, g0, be0, b1, Y2,
                                        sum2, sq2);
  bnrelu_out_kernel<<<4096, 256, 0, stream>>>(Y2, sum2, sq2, g1, be1, outF);
}